// Round 4
// baseline (242.328 us; speedup 1.0000x reference)
//
#include <hip/hip_runtime.h>
#include <hip/hip_bf16.h>

// Round 8:
//   k1 qkv: unchanged (round 7).
//   k2 attn: REWRITE to 32x32x16 MFMA. Theory: kernel was LDS-BW-bound
//           (8 waves x 64KB LDS reads/iter = 512KB/CU/iter ~ 6150cyc -> 82us of
//           110us wall). New: 8 waves = 4 q-groups x 2 kv-halves; each wave owns
//           32 q-rows and reads only its 32-k half of K + 32-s half of V^T
//           (32KB/iter per wave) -> LDS traffic per q-row HALVED.
//           Same staging (BN=64 double-buffered 128KB, gl_lds src-XOR swizzle).
//           Softmax in 32x32 C-layout: 16 lane-local + 1 shfl_xor(32).
//           P^T B-frags: 8 pack2 + 8 shfl_xor(32) + selects. kv-half merge via
//           LDS at end (round-4/5 verified pattern, bf16 scratch).
//   k3 proj: unchanged (round 7).
// ws (ushort): Q/ctx[0], K[NE], Vt[2NE], NE=16*2048*256.

typedef short bf16x8 __attribute__((ext_vector_type(8)));
typedef float f32x4 __attribute__((ext_vector_type(4)));
typedef float f32x16 __attribute__((ext_vector_type(16)));

#define MFMA16(a, b, c) __builtin_amdgcn_mfma_f32_16x16x32_bf16((a), (b), (c), 0, 0, 0)
#define MFMA32(a, b, c) __builtin_amdgcn_mfma_f32_32x32x16_bf16((a), (b), (c), 0, 0, 0)

__device__ __forceinline__ unsigned short f2bf(float f) {
  unsigned int x;
  __builtin_memcpy(&x, &f, 4);
  x = x + 0x7fffu + ((x >> 16) & 1u);
  return (unsigned short)(x >> 16);
}
__device__ __forceinline__ unsigned int pack2(float a, float b) {
  float2 t;
  t.x = a;
  t.y = b;
  __hip_bfloat162 h = __float22bfloat162_rn(t);
  unsigned int u;
  __builtin_memcpy(&u, &h, 4);
  return u;
}
__device__ __forceinline__ float bfu2f(unsigned int lo16) {
  // lo16 = bf16 bits in the LOW 16 bits
  unsigned int v = lo16 << 16;
  float f;
  __builtin_memcpy(&f, &v, 4);
  return f;
}

// async 16B global->LDS. LDS dest is wave-uniform base + lane*16 (HW rule);
// pointers passed via integer casts (AS3 = low 32 bits of flat LDS addr).
typedef __attribute__((address_space(3))) void as3_void;
typedef __attribute__((address_space(1))) const void as1_void;
__device__ __forceinline__ void gl_lds16(const void* g, void* l) {
  __builtin_amdgcn_global_load_lds((as1_void*)(unsigned long long)g,
                                   (as3_void*)(unsigned int)(unsigned long long)l,
                                   16, 0, 0);
}

// ---------------- QKV GEMM ----------------
// grid(256), block 512 (8 waves). m-tile 128 rows; A = x tile (full K=256) in LDS
// once; loop n0 = 0..640 step 128 staging B each time. fp32->bf16 on staging.
__global__ __launch_bounds__(512, 1) void qkv_kernel(
    const float* __restrict__ X, const float* __restrict__ W,
    unsigned short* __restrict__ Q, unsigned short* __restrict__ Kp,
    unsigned short* __restrict__ Vt) {
  __shared__ unsigned short Al[128 * 256];
  __shared__ unsigned short Bl[128 * 256];
  const int m0 = blockIdx.x * 128;
  const int t = threadIdx.x;
  const int w = t >> 6, lane = t & 63, lo = lane & 15, quad = lane >> 4;
  const int wr = (w >> 2) * 64, wc = (w & 3) * 32;

#pragma unroll
  for (int r = 0; r < 8; ++r) {
    int ci = r * 512 + t;
    int row = ci >> 5, c = ci & 31;
    int s = (c & 24) | ((c ^ (row & 7)) & 7);
    const float* xp = X + (size_t)(m0 + row) * 256 + c * 8;
    float4 a0 = *(const float4*)xp, a1 = *(const float4*)(xp + 4);
    uint4 ua;
    ua.x = pack2(a0.x, a0.y);
    ua.y = pack2(a0.z, a0.w);
    ua.z = pack2(a1.x, a1.y);
    ua.w = pack2(a1.z, a1.w);
    *(uint4*)(&Al[row * 256 + s * 8]) = ua;
  }

  for (int n = 0; n < 6; ++n) {
    const int n0 = n * 128;
    if (n > 0) __syncthreads();
#pragma unroll
    for (int r = 0; r < 8; ++r) {
      int ci = r * 512 + t;
      int row = ci >> 5, c = ci & 31;
      int s = (c & 24) | ((c ^ (row & 7)) & 7);
      const float* wp = W + (size_t)(n0 + row) * 256 + c * 8;
      float4 b0 = *(const float4*)wp, b1 = *(const float4*)(wp + 4);
      uint4 ub;
      ub.x = pack2(b0.x, b0.y);
      ub.y = pack2(b0.z, b0.w);
      ub.z = pack2(b1.x, b1.y);
      ub.w = pack2(b1.z, b1.w);
      *(uint4*)(&Bl[row * 256 + s * 8]) = ub;
    }
    __syncthreads();

    f32x4 zero4 = {0.f, 0.f, 0.f, 0.f};
    f32x4 acc[4][2];
#pragma unroll
    for (int i = 0; i < 4; i++)
#pragma unroll
      for (int j = 0; j < 2; j++) acc[i][j] = zero4;

#pragma unroll
    for (int kc = 0; kc < 8; ++kc) {
      const int c = kc * 4 + quad;
      const int jj = (c & 24) | ((c ^ (lo & 7)) & 7);
      bf16x8 af[4], bfr[2];
#pragma unroll
      for (int mt = 0; mt < 4; ++mt)
        af[mt] = *(const bf16x8*)(&Al[(wr + mt * 16 + lo) * 256 + jj * 8]);
#pragma unroll
      for (int nt = 0; nt < 2; ++nt)
        bfr[nt] = *(const bf16x8*)(&Bl[(wc + nt * 16 + lo) * 256 + jj * 8]);
#pragma unroll
      for (int mt = 0; mt < 4; ++mt)
#pragma unroll
        for (int nt = 0; nt < 2; ++nt)
          acc[mt][nt] = MFMA16(af[mt], bfr[nt], acc[mt][nt]);
    }

    const int mb = m0 + wr, nb = n0 + wc;
    if (n0 < 256) {
#pragma unroll
      for (int mt = 0; mt < 4; ++mt)
#pragma unroll
        for (int nt = 0; nt < 2; ++nt) {
          int m = mb + mt * 16 + quad * 4;
          int nn = nb + nt * 16 + lo;
          unsigned short* p = Q + (size_t)m * 256 + nn;
          p[0] = f2bf(acc[mt][nt][0]);
          p[256] = f2bf(acc[mt][nt][1]);
          p[512] = f2bf(acc[mt][nt][2]);
          p[768] = f2bf(acc[mt][nt][3]);
        }
    } else if (n0 < 512) {
#pragma unroll
      for (int mt = 0; mt < 4; ++mt)
#pragma unroll
        for (int nt = 0; nt < 2; ++nt) {
          int m = mb + mt * 16 + quad * 4;
          int nn = nb + nt * 16 + lo - 256;
          unsigned short* p = Kp + (size_t)m * 256 + nn;
          p[0] = f2bf(acc[mt][nt][0]);
          p[256] = f2bf(acc[mt][nt][1]);
          p[512] = f2bf(acc[mt][nt][2]);
          p[768] = f2bf(acc[mt][nt][3]);
        }
    } else {
#pragma unroll
      for (int mt = 0; mt < 4; ++mt)
#pragma unroll
        for (int nt = 0; nt < 2; ++nt) {
          int m = mb + mt * 16 + quad * 4;
          int d = nb + nt * 16 + lo - 512;
          int b = m >> 11, s = m & 2047;
          uint2 v;
          v.x = pack2(acc[mt][nt][0], acc[mt][nt][1]);
          v.y = pack2(acc[mt][nt][2], acc[mt][nt][3]);
          *(uint2*)(Vt + ((size_t)(b * 256 + d)) * 2048 + s) = v;
        }
    }
  }
}

// ---------------- Flash attention, 32x32 MFMA, kv-half split ----------------
// grid(256) = 16 b x 16 qt. block 512 = 8 waves: wave w -> q-group qg=w&3
// (32 q-rows), kv-half hh=w>>2 (k-rows hh*32..+31 of each staged 64-tile).
// 32 iters, BN=64. LDS buf p in {0,1} (32768 ushorts): [K 64x256 | V^T 256x64].
//   K chunk (row,c') holds global col-chunk c' ^ (row&31)   (involution).
//   V chunk (d,s')  holds global s-chunk  s' ^ (d&7).
// Per wave per iter: 16 K-frag + 16 V-frag b128 reads = 32KB (half of before
// per q-row). Final kv-half merge via LDS scratch.
__global__ __launch_bounds__(512, 2) void attn_kernel(
    const unsigned short* __restrict__ Q, const unsigned short* __restrict__ K,
    const unsigned short* __restrict__ Vt, unsigned short* __restrict__ C) {
  __shared__ __attribute__((aligned(16))) unsigned short smem[65536];  // 131072 B
  const int id = blockIdx.x;
  const int b = id & 15;
  const int qt = id >> 4;
  const int t = threadIdx.x;
  const int w = t >> 6, lane = t & 63, lq = lane & 31, hi = lane >> 5;
  const int hh = w >> 2, qg = w & 3;
  constexpr float SCALE_LOG2E = 0.0625f * 1.4426950408889634f;

  const unsigned short* Kb = K + (size_t)b * 2048 * 256;
  const unsigned short* Vb = Vt + (size_t)b * 256 * 2048;

  // --- staging setup: 8 chunks/thread (4 K + 4 V) ---
  unsigned int gkoff[4], gvoff[4];  // byte offsets from Kb / Vb
  int loK[4], loV[4];               // wave-uniform LDS ushort offsets
#pragma unroll
  for (int r = 0; r < 4; ++r) {
    int ck = r * 512 + t;  // K: row=ck>>5 (0..63), slot=ck&31
    int krow = ck >> 5, kc = ck & 31;
    int ksrc = kc ^ (krow & 31);
    gkoff[r] = (unsigned int)((krow * 256 + ksrc * 8) * 2);
    loK[r] = __builtin_amdgcn_readfirstlane((r * 512 + w * 64) * 8);

    int cv = r * 512 + t;  // V: d=cv>>3 (0..255), slot=cv&7
    int vd = cv >> 3, vs = cv & 7;
    int vsrc = vs ^ (vd & 7);
    gvoff[r] = (unsigned int)((vd * 2048 + vsrc * 8) * 2);
    loV[r] = __builtin_amdgcn_readfirstlane(16384 + (r * 512 + w * 64) * 8);
  }

  // --- Q fragments (B-operand, 32x32x16): lane q=lq, d = st*16 + hi*8 + j ---
  const int qrow = b * 2048 + qt * 128 + qg * 32 + lq;
  const unsigned short* qp = Q + (size_t)qrow * 256;
  bf16x8 qf[16];
#pragma unroll
  for (int st = 0; st < 16; ++st)
    qf[st] = *(const bf16x8*)(qp + st * 16 + hi * 8);

  f32x16 oacc[8];
#pragma unroll
  for (int i = 0; i < 8; i++) oacc[i] = 0.f;
  float m_run = -1e30f, l_run = 0.f;

  // prologue: prefetch iter 0 into buffer 0
#pragma unroll
  for (int r = 0; r < 4; ++r) {
    gl_lds16((const char*)Kb + gkoff[r], &smem[loK[r]]);
    gkoff[r] += 64 * 256 * 2;
  }
#pragma unroll
  for (int r = 0; r < 4; ++r) {
    gl_lds16((const char*)Vb + gvoff[r], &smem[loV[r]]);
    gvoff[r] += 64 * 2;
  }

  for (int it = 0; it < 32; ++it) {
    asm volatile("s_waitcnt vmcnt(0)" ::: "memory");
    __syncthreads();
    if (it < 31) {
      const int pn = ((it + 1) & 1) * 32768;
#pragma unroll
      for (int r = 0; r < 4; ++r) {
        gl_lds16((const char*)Kb + gkoff[r], &smem[pn + loK[r]]);
        gkoff[r] += 64 * 256 * 2;
      }
#pragma unroll
      for (int r = 0; r < 4; ++r) {
        gl_lds16((const char*)Vb + gvoff[r], &smem[pn + loV[r]]);
        gvoff[r] += 64 * 2;
      }
    }
    const unsigned short* Kl = smem + (it & 1) * 32768;
    const unsigned short* Vl = Kl + 16384;

    // S^T[32k x 32q] for this wave's kv-half: A = K rows hh*32+lq, B = Q.
    // Two accumulators break the 16-long dependent MFMA chain.
    f32x16 s0 = 0.f, s1 = 0.f;
    __builtin_amdgcn_s_setprio(1);
#pragma unroll
    for (int st = 0; st < 16; ++st) {
      const int slot = (st * 2 + hi) ^ lq;
      bf16x8 kf = *(const bf16x8*)(&Kl[(hh * 32 + lq) * 256 + slot * 8]);
      if (st & 1)
        s1 = MFMA32(kf, qf[st], s1);
      else
        s0 = MFMA32(kf, qf[st], s0);
    }
    __builtin_amdgcn_s_setprio(0);

    // online softmax: lane owns q=lq; 16 k-vals at rows (i&3)+8*(i>>2)+4*hi.
    float p[16];
    float cmax = -1e30f;
#pragma unroll
    for (int i = 0; i < 16; i++) {
      p[i] = (s0[i] + s1[i]) * SCALE_LOG2E;
      cmax = fmaxf(cmax, p[i]);
    }
    cmax = fmaxf(cmax, __shfl_xor(cmax, 32));
    // T13 defer-rescale
    if (!__all(cmax <= m_run + 8.f)) {
      float mnew = fmaxf(m_run, cmax);
      float alpha = exp2f(m_run - mnew);
      l_run *= alpha;
#pragma unroll
      for (int i = 0; i < 8; i++) oacc[i] *= alpha;
      m_run = mnew;
    }
    float rsum = 0.f;
#pragma unroll
    for (int i = 0; i < 16; i++) {
      p[i] = exp2f(p[i] - m_run);
      rsum += p[i];
    }
    rsum += __shfl_xor(rsum, 32);
    l_run += rsum;

    // --- P^T B-frag, contraction step ss=0 (s_local 0..15) ---
    // lane(hi=0) holds s {0-3,8-11,...}, lane(hi=1) holds s {4-7,12-15,...}.
    {
      unsigned int x0 = pack2(p[0], p[1]), x1 = pack2(p[2], p[3]);
      unsigned int y0 = pack2(p[4], p[5]), y1 = pack2(p[6], p[7]);
      unsigned int ex0 = (unsigned int)__shfl_xor((int)x0, 32);
      unsigned int ex1 = (unsigned int)__shfl_xor((int)x1, 32);
      unsigned int ey0 = (unsigned int)__shfl_xor((int)y0, 32);
      unsigned int ey1 = (unsigned int)__shfl_xor((int)y1, 32);
      union {
        unsigned int u[4];
        bf16x8 v;
      } cvt;
      cvt.u[0] = hi ? ey0 : x0;
      cvt.u[1] = hi ? ey1 : x1;
      cvt.u[2] = hi ? y0 : ex0;
      cvt.u[3] = hi ? y1 : ex1;
      bf16x8 pf = cvt.v;
      __builtin_amdgcn_s_setprio(1);
#pragma unroll
      for (int dt = 0; dt < 8; ++dt) {
        const int slot = (hh * 4 + hi) ^ (lq & 7);
        bf16x8 vf = *(const bf16x8*)(&Vl[(dt * 32 + lq) * 64 + slot * 8]);
        oacc[dt] = MFMA32(vf, pf, oacc[dt]);
      }
      __builtin_amdgcn_s_setprio(0);
    }
    // --- step ss=1 (s_local 16..31) ---
    {
      unsigned int z0 = pack2(p[8], p[9]), z1 = pack2(p[10], p[11]);
      unsigned int w0 = pack2(p[12], p[13]), w1 = pack2(p[14], p[15]);
      unsigned int ez0 = (unsigned int)__shfl_xor((int)z0, 32);
      unsigned int ez1 = (unsigned int)__shfl_xor((int)z1, 32);
      unsigned int ew0 = (unsigned int)__shfl_xor((int)w0, 32);
      unsigned int ew1 = (unsigned int)__shfl_xor((int)w1, 32);
      union {
        unsigned int u[4];
        bf16x8 v;
      } cvt;
      cvt.u[0] = hi ? ew0 : z0;
      cvt.u[1] = hi ? ew1 : z1;
      cvt.u[2] = hi ? w0 : ez0;
      cvt.u[3] = hi ? w1 : ez1;
      bf16x8 pf = cvt.v;
      __builtin_amdgcn_s_setprio(1);
#pragma unroll
      for (int dt = 0; dt < 8; ++dt) {
        const int slot = (hh * 4 + 2 + hi) ^ (lq & 7);
        bf16x8 vf = *(const bf16x8*)(&Vl[(dt * 32 + lq) * 64 + slot * 8]);
        oacc[dt] = MFMA32(vf, pf, oacc[dt]);
      }
      __builtin_amdgcn_s_setprio(0);
    }
  }

  // ---- merge the two kv-halves; smem reused as scratch after full barrier ----
  __syncthreads();
  float* st = (float*)smem;  // m[256], l[256]
  if (hi == 0) {
    st[w * 32 + lq] = m_run;
    st[256 + w * 32 + lq] = l_run;
  }
  __syncthreads();
  float m_o = st[(w ^ 4) * 32 + lq];
  float l_o = st[256 + (w ^ 4) * 32 + lq];
  float m_tot = fmaxf(m_run, m_o);
  float f_self = exp2f(m_run - m_tot);
  float l_tot = l_run * f_self + l_o * exp2f(m_o - m_tot);
  // Of: bf16 [qg][32 q][264 d-padded], at ushort offset 1024
  unsigned short* Of = smem + 1024;
  if (hh == 1) {
#pragma unroll
    for (int dt = 0; dt < 8; ++dt)
#pragma unroll
      for (int i = 0; i < 16; i += 2) {
        int d = dt * 32 + (i & 3) + 8 * (i >> 2) + 4 * hi;
        *(unsigned int*)&Of[qg * 8448 + lq * 264 + d] =
            pack2(oacc[dt][i] * f_self, oacc[dt][i + 1] * f_self);
      }
  }
  __syncthreads();
  if (hh == 0) {
    float inv = 1.0f / l_tot;
    unsigned short* cp = C + (size_t)qrow * 256;
#pragma unroll
    for (int dt = 0; dt < 8; ++dt)
#pragma unroll
      for (int i = 0; i < 16; i += 2) {
        int d = dt * 32 + (i & 3) + 8 * (i >> 2) + 4 * hi;
        unsigned int u = *(unsigned int*)&Of[qg * 8448 + lq * 264 + d];
        float o0 = oacc[dt][i] * f_self + bfu2f(u & 0xffffu);
        float o1 = oacc[dt][i + 1] * f_self + bfu2f(u >> 16);
        *(unsigned int*)(cp + d) = pack2(o0 * inv, o1 * inv);
      }
  }
}

// ---------------- Output projection ----------------
__global__ __launch_bounds__(512, 1) void proj_kernel(
    const unsigned short* __restrict__ Xc, const float* __restrict__ W,
    const float* __restrict__ bias, float* __restrict__ out) {
  __shared__ unsigned short Al[128 * 256];
  __shared__ unsigned short Bl[128 * 256];
  const int m0 = blockIdx.x * 128;
  const int t = threadIdx.x;
  const int w = t >> 6, lane = t & 63, lo = lane & 15, quad = lane >> 4;
  const int wr = (w >> 2) * 64, wc = (w & 3) * 32;

  const unsigned short* Xb = Xc + (size_t)m0 * 256;
#pragma unroll
  for (int r = 0; r < 8; ++r) {
    int idx = r * 512 + t;
    int row = idx >> 5, sc = idx & 31;
    int c = (sc & 24) | ((sc ^ (row & 7)) & 7);
    int lofs = __builtin_amdgcn_readfirstlane((r * 512 + w * 64) * 8);
    gl_lds16(Xb + (size_t)row * 256 + c * 8, &Al[lofs]);
  }

  for (int n = 0; n < 2; ++n) {
    const int n0 = n * 128;
    if (n > 0) __syncthreads();
#pragma unroll
    for (int r = 0; r < 8; ++r) {
      int ci = r * 512 + t;
      int row = ci >> 5, c = ci & 31;
      int s = (c & 24) | ((c ^ (row & 7)) & 7);
      const float* wp = W + (size_t)(n0 + row) * 256 + c * 8;
      float4 b0 = *(const float4*)wp, b1 = *(const float4*)(wp + 4);
      uint4 ub;
      ub.x = pack2(b0.x, b0.y);
      ub.y = pack2(b0.z, b0.w);
      ub.z = pack2(b1.x, b1.y);
      ub.w = pack2(b1.z, b1.w);
      *(uint4*)(&Bl[row * 256 + s * 8]) = ub;
    }
    if (n == 0) asm volatile("s_waitcnt vmcnt(0)" ::: "memory");
    __syncthreads();

    f32x4 zero4 = {0.f, 0.f, 0.f, 0.f};
    f32x4 acc[4][2];
#pragma unroll
    for (int i = 0; i < 4; i++)
#pragma unroll
      for (int j = 0; j < 2; j++) acc[i][j] = zero4;

#pragma unroll
    for (int kc = 0; kc < 8; ++kc) {
      const int c = kc * 4 + quad;
      const int jj = (c & 24) | ((c ^ (lo & 7)) & 7);
      bf16x8 af[4], bfr[2];
#pragma unroll
      for (int mt = 0; mt < 4; ++mt)
        af[mt] = *(const bf16x8*)(&Al[(wr + mt * 16 + lo) * 256 + jj * 8]);
#pragma unroll
      for (int nt = 0; nt < 2; ++nt)
        bfr[nt] = *(const bf16x8*)(&Bl[(wc + nt * 16 + lo) * 256 + jj * 8]);
#pragma unroll
      for (int mt = 0; mt < 4; ++mt)
#pragma unroll
        for (int nt = 0; nt < 2; ++nt)
          acc[mt][nt] = MFMA16(af[mt], bfr[nt], acc[mt][nt]);
    }

    const int mb = m0 + wr, nb = n0 + wc;
#pragma unroll
    for (int nt = 0; nt < 2; ++nt) {
      int nn = nb + nt * 16 + lo;
      float bv = bias[nn];
#pragma unroll
      for (int mt = 0; mt < 4; ++mt) {
        int m = mb + mt * 16 + quad * 4;
        float* p = out + (size_t)m * 256 + nn;
        p[0] = acc[mt][nt][0] + bv;
        p[256] = acc[mt][nt][1] + bv;
        p[512] = acc[mt][nt][2] + bv;
        p[768] = acc[mt][nt][3] + bv;
      }
    }
  }
}

extern "C" void kernel_launch(void* const* d_in, const int* in_sizes, int n_in,
                              void* d_out, int out_size, void* d_ws, size_t ws_size,
                              hipStream_t stream) {
  const float* X = (const float*)d_in[0];
  const float* Wq = (const float*)d_in[1];
  const float* Wo = (const float*)d_in[2];
  const float* Bo = (const float*)d_in[3];
  float* out = (float*)d_out;
  unsigned short* ws = (unsigned short*)d_ws;

  const size_t NE = (size_t)16 * 2048 * 256;
  unsigned short* Qb = ws;
  unsigned short* Kb = ws + NE;
  unsigned short* Vt = ws + 2 * NE;
  unsigned short* Cx = ws;  // ctx aliases Q (per-block private rows)

  qkv_kernel<<<dim3(256), 512, 0, stream>>>(X, Wq, Qb, Kb, Vt);
  attn_kernel<<<dim3(256), 512, 0, stream>>>(Qb, Kb, Vt, Cx);
  proj_kernel<<<dim3(256), 512, 0, stream>>>(Cx, Wo, Bo, out);
}

// Round 5
// 212.191 us; speedup vs baseline: 1.1420x; 1.1420x over previous
//
#include <hip/hip_runtime.h>
#include <hip/hip_bf16.h>

// Round 9:
//   k0 cvtw: NEW. Pre-convert W_qkv (768x256 fp32) -> bf16, PRE-SWIZZLED into
//           the chunk layout qkv's LDS expects (chunk sc of row holds global
//           chunk c=(sc&24)|((sc^(row&7))&7)). Output lives in d_out (unused
//           until proj; qkv is the only reader; proj overwrites later).
//   k1 qkv: B-staging switched from cvt-stage (fp32 load+pack2+ds_write chains,
//           ~600 VALU/thread, 1 block/CU -> exposed L2 latency x6) to pure
//           global_load_lds from Wqbf: 8 async 16B chunks/thread, ZERO VALU.
//           A-stage (X, read once) unchanged. Everything else round-7.
//   k2 attn: REVERTED to round-6 verbatim (verified 110us; R8's 32x32 rewrite
//           needed 240 live regs -> spilled 15MB scratch, 137us).
//   k3 proj: unchanged (round 7).
// ws (ushort): Q/ctx[0], K[NE], Vt[2NE], NE=16*2048*256. Wqbf in d_out.

typedef short bf16x8 __attribute__((ext_vector_type(8)));
typedef float f32x4 __attribute__((ext_vector_type(4)));

#define MFMA16(a, b, c) __builtin_amdgcn_mfma_f32_16x16x32_bf16((a), (b), (c), 0, 0, 0)

__device__ __forceinline__ unsigned short f2bf(float f) {
  unsigned int x;
  __builtin_memcpy(&x, &f, 4);
  x = x + 0x7fffu + ((x >> 16) & 1u);
  return (unsigned short)(x >> 16);
}
__device__ __forceinline__ unsigned int pack2(float a, float b) {
  float2 t;
  t.x = a;
  t.y = b;
  __hip_bfloat162 h = __float22bfloat162_rn(t);
  unsigned int u;
  __builtin_memcpy(&u, &h, 4);
  return u;
}

// async 16B global->LDS. LDS dest is wave-uniform base + lane*16 (HW rule);
// pointers passed via integer casts (AS3 = low 32 bits of flat LDS addr).
typedef __attribute__((address_space(3))) void as3_void;
typedef __attribute__((address_space(1))) const void as1_void;
__device__ __forceinline__ void gl_lds16(const void* g, void* l) {
  __builtin_amdgcn_global_load_lds((as1_void*)(unsigned long long)g,
                                   (as3_void*)(unsigned int)(unsigned long long)l,
                                   16, 0, 0);
}

// ---------------- W pre-convert (fp32 -> bf16, pre-swizzled) ----------------
// 768 rows x 32 chunks = 24576 chunks, 1 chunk (16B out) per thread.
__global__ __launch_bounds__(256, 4) void cvtw_kernel(
    const float* __restrict__ W, unsigned short* __restrict__ Wbf) {
  int idx = blockIdx.x * 256 + threadIdx.x;
  int row = idx >> 5, sc = idx & 31;
  int c = (sc & 24) | ((sc ^ (row & 7)) & 7);
  const float* wp = W + (size_t)row * 256 + c * 8;
  float4 a0 = *(const float4*)wp, a1 = *(const float4*)(wp + 4);
  uint4 u;
  u.x = pack2(a0.x, a0.y);
  u.y = pack2(a0.z, a0.w);
  u.z = pack2(a1.x, a1.y);
  u.w = pack2(a1.z, a1.w);
  *(uint4*)(Wbf + (size_t)idx * 8) = u;
}

// ---------------- QKV GEMM ----------------
// grid(256), block 512 (8 waves). m-tile 128 rows; A = x tile (full K=256) in LDS
// once (cvt-staged, read-once); loop n0 = 0..640 step 128, B staged via pure
// async global_load_lds from pre-swizzled Wqbf (zero VALU).
// Wave w -> (wr = (w>>2)*64 rows, wc = (w&3)*32 cols), acc[4][2].
__global__ __launch_bounds__(512, 1) void qkv_kernel(
    const float* __restrict__ X, const unsigned short* __restrict__ Wqbf,
    unsigned short* __restrict__ Q, unsigned short* __restrict__ Kp,
    unsigned short* __restrict__ Vt) {
  __shared__ unsigned short Al[128 * 256];  // 64KB, chunk-swizzle low3
  __shared__ unsigned short Bl[128 * 256];  // 64KB
  const int m0 = blockIdx.x * 128;
  const int t = threadIdx.x;
  const int w = t >> 6, lane = t & 63, lo = lane & 15, quad = lane >> 4;
  const int wr = (w >> 2) * 64, wc = (w & 3) * 32;

  // stage A once: 4096 chunks, 8 per thread (fp32->bf16 cvt, read-once data)
#pragma unroll
  for (int r = 0; r < 8; ++r) {
    int ci = r * 512 + t;
    int row = ci >> 5, c = ci & 31;
    int s = (c & 24) | ((c ^ (row & 7)) & 7);
    const float* xp = X + (size_t)(m0 + row) * 256 + c * 8;
    float4 a0 = *(const float4*)xp, a1 = *(const float4*)(xp + 4);
    uint4 ua;
    ua.x = pack2(a0.x, a0.y);
    ua.y = pack2(a0.z, a0.w);
    ua.z = pack2(a1.x, a1.y);
    ua.w = pack2(a1.z, a1.w);
    *(uint4*)(&Al[row * 256 + s * 8]) = ua;
  }

  for (int n = 0; n < 6; ++n) {
    const int n0 = n * 128;
    if (n > 0) __syncthreads();  // prev compute done before overwriting Bl
    // B-stage: pure async gl_lds; Wqbf already bf16 + pre-swizzled, so the
    // source is LINEAR: chunk idx (row,sc) of the tile -> Wqbf[(n0+row)*256+sc*8].
    {
      const unsigned short* Wb = Wqbf + (size_t)n0 * 256;
      int lofs = __builtin_amdgcn_readfirstlane(w * 64 * 8);
#pragma unroll
      for (int r = 0; r < 8; ++r) {
        gl_lds16(Wb + (size_t)(r * 512 + t) * 8, &Bl[r * 512 * 8 + lofs]);
      }
    }
    asm volatile("s_waitcnt vmcnt(0)" ::: "memory");
    __syncthreads();

    f32x4 zero4 = {0.f, 0.f, 0.f, 0.f};
    f32x4 acc[4][2];
#pragma unroll
    for (int i = 0; i < 4; i++)
#pragma unroll
      for (int j = 0; j < 2; j++) acc[i][j] = zero4;

#pragma unroll
    for (int kc = 0; kc < 8; ++kc) {  // K=256 in 8 MFMA steps
      const int c = kc * 4 + quad;
      const int jj = (c & 24) | ((c ^ (lo & 7)) & 7);
      bf16x8 af[4], bfr[2];
#pragma unroll
      for (int mt = 0; mt < 4; ++mt)
        af[mt] = *(const bf16x8*)(&Al[(wr + mt * 16 + lo) * 256 + jj * 8]);
#pragma unroll
      for (int nt = 0; nt < 2; ++nt)
        bfr[nt] = *(const bf16x8*)(&Bl[(wc + nt * 16 + lo) * 256 + jj * 8]);
#pragma unroll
      for (int mt = 0; mt < 4; ++mt)
#pragma unroll
        for (int nt = 0; nt < 2; ++nt)
          acc[mt][nt] = MFMA16(af[mt], bfr[nt], acc[mt][nt]);
    }

    // epilogue for this n-tile
    const int mb = m0 + wr, nb = n0 + wc;
    if (n0 < 256) {
#pragma unroll
      for (int mt = 0; mt < 4; ++mt)
#pragma unroll
        for (int nt = 0; nt < 2; ++nt) {
          int m = mb + mt * 16 + quad * 4;
          int nn = nb + nt * 16 + lo;
          unsigned short* p = Q + (size_t)m * 256 + nn;
          p[0] = f2bf(acc[mt][nt][0]);
          p[256] = f2bf(acc[mt][nt][1]);
          p[512] = f2bf(acc[mt][nt][2]);
          p[768] = f2bf(acc[mt][nt][3]);
        }
    } else if (n0 < 512) {
#pragma unroll
      for (int mt = 0; mt < 4; ++mt)
#pragma unroll
        for (int nt = 0; nt < 2; ++nt) {
          int m = mb + mt * 16 + quad * 4;
          int nn = nb + nt * 16 + lo - 256;
          unsigned short* p = Kp + (size_t)m * 256 + nn;
          p[0] = f2bf(acc[mt][nt][0]);
          p[256] = f2bf(acc[mt][nt][1]);
          p[512] = f2bf(acc[mt][nt][2]);
          p[768] = f2bf(acc[mt][nt][3]);
        }
    } else {
#pragma unroll
      for (int mt = 0; mt < 4; ++mt)
#pragma unroll
        for (int nt = 0; nt < 2; ++nt) {
          int m = mb + mt * 16 + quad * 4;
          int d = nb + nt * 16 + lo - 512;
          int b = m >> 11, s = m & 2047;
          uint2 v;
          v.x = pack2(acc[mt][nt][0], acc[mt][nt][1]);
          v.y = pack2(acc[mt][nt][2], acc[mt][nt][3]);
          *(uint2*)(Vt + ((size_t)(b * 256 + d)) * 2048 + s) = v;
        }
    }
  }
}

// ---------------- Flash attention, single KV stream, BN=64 ----------------
// (round-6 verbatim: verified 110.6us, VGPR 112, no spills)
// grid(256) = 16 b x 16 qt, exactly 1 block/CU. block 512 = 8 waves, wave w owns
// q-rows qt*128 + w*16 .. +16. 32 iters over kv (BN=64).
// LDS buf p in {0,1} (32768 ushorts each): [K 64x256 | V^T 256x64].
//   K chunk (row,j) holds global col-chunk (j&16)|((j^(row&15))&15).
//   V chunk (d,slot) holds global s-chunk slot^(d&7)  (128B stride, 8-slot XOR).
__global__ __launch_bounds__(512, 2) void attn_kernel(
    const unsigned short* __restrict__ Q, const unsigned short* __restrict__ K,
    const unsigned short* __restrict__ Vt, unsigned short* __restrict__ C) {
  __shared__ __attribute__((aligned(16))) unsigned short smem[65536];  // 131072 B
  const int id = blockIdx.x;
  const int b = id & 15;
  const int qt = id >> 4;
  const int t = threadIdx.x;
  const int w = t >> 6, lane = t & 63, lo = lane & 15, quad = lane >> 4;
  constexpr float SCALE_LOG2E = 0.0625f * 1.4426950408889634f;

  const unsigned short* Kb = K + (size_t)b * 2048 * 256;
  const unsigned short* Vb = Vt + (size_t)b * 256 * 2048;

  unsigned int gkoff[4], gvoff[4];
  int loK[4], loV[4];
#pragma unroll
  for (int r = 0; r < 4; ++r) {
    int ck = r * 512 + t;
    int row = ck >> 5, j = ck & 31;
    int srcj = (j & 16) | ((j ^ (row & 15)) & 15);
    gkoff[r] = (unsigned int)((row * 256 + srcj * 8) * 2);
    loK[r] = __builtin_amdgcn_readfirstlane((r * 512 + w * 64) * 8);

    int cv = r * 512 + t;
    int d = cv >> 3, slot = cv & 7;
    int g = slot ^ (d & 7);
    gvoff[r] = (unsigned int)((d * 2048 + g * 8) * 2);
    loV[r] = __builtin_amdgcn_readfirstlane(16384 + (r * 512 + w * 64) * 8);
  }

  const int qrow = b * 2048 + qt * 128 + w * 16 + lo;
  const unsigned short* qp = Q + (size_t)qrow * 256;
  bf16x8 qf[8];
#pragma unroll
  for (int ks = 0; ks < 8; ++ks)
    qf[ks] = *(const bf16x8*)(qp + ks * 32 + quad * 8);

  f32x4 zero4 = {0.f, 0.f, 0.f, 0.f};
  f32x4 oacc[16];
#pragma unroll
  for (int i = 0; i < 16; i++) oacc[i] = zero4;
  float m_run = -1e30f, l_run = 0.f;

#pragma unroll
  for (int r = 0; r < 4; ++r) {
    gl_lds16((const char*)Kb + gkoff[r], &smem[loK[r]]);
    gkoff[r] += 64 * 256 * 2;
  }
#pragma unroll
  for (int r = 0; r < 4; ++r) {
    gl_lds16((const char*)Vb + gvoff[r], &smem[loV[r]]);
    gvoff[r] += 64 * 2;
  }

  for (int it = 0; it < 32; ++it) {
    asm volatile("s_waitcnt vmcnt(0)" ::: "memory");
    __syncthreads();
    if (it < 31) {
      const int pn = ((it + 1) & 1) * 32768;
#pragma unroll
      for (int r = 0; r < 4; ++r) {
        gl_lds16((const char*)Kb + gkoff[r], &smem[pn + loK[r]]);
        gkoff[r] += 64 * 256 * 2;
      }
#pragma unroll
      for (int r = 0; r < 4; ++r) {
        gl_lds16((const char*)Vb + gvoff[r], &smem[pn + loV[r]]);
        gvoff[r] += 64 * 2;
      }
    }
    const unsigned short* Kl = smem + (it & 1) * 32768;
    const unsigned short* Vl = Kl + 16384;

    f32x4 sacc[4];
#pragma unroll
    for (int r = 0; r < 4; ++r) sacc[r] = zero4;
    __builtin_amdgcn_s_setprio(1);
#pragma unroll
    for (int ks = 0; ks < 8; ++ks) {
      const int c = ks * 4 + quad;
      const int jj = (c & 16) | ((c ^ lo) & 15);
#pragma unroll
      for (int r = 0; r < 4; ++r) {
        bf16x8 kf = *(const bf16x8*)(&Kl[(r * 16 + lo) * 256 + jj * 8]);
        sacc[r] = MFMA16(kf, qf[ks], sacc[r]);
      }
    }
    __builtin_amdgcn_s_setprio(0);

    float p[4][4];
    float cmax = -1e30f;
#pragma unroll
    for (int r = 0; r < 4; r++)
#pragma unroll
      for (int i = 0; i < 4; i++) {
        p[r][i] = sacc[r][i] * SCALE_LOG2E;
        cmax = fmaxf(cmax, p[r][i]);
      }
    cmax = fmaxf(cmax, __shfl_xor(cmax, 16));
    cmax = fmaxf(cmax, __shfl_xor(cmax, 32));
    if (!__all(cmax <= m_run + 8.f)) {
      float mnew = fmaxf(m_run, cmax);
      float alpha = exp2f(m_run - mnew);
      l_run *= alpha;
#pragma unroll
      for (int i = 0; i < 16; i++) oacc[i] *= alpha;
      m_run = mnew;
    }
    float rsum = 0.f;
#pragma unroll
    for (int r = 0; r < 4; r++)
#pragma unroll
      for (int i = 0; i < 4; i++) {
        p[r][i] = exp2f(p[r][i] - m_run);
        rsum += p[r][i];
      }
    rsum += __shfl_xor(rsum, 16);
    rsum += __shfl_xor(rsum, 32);
    l_run += rsum;

    unsigned int pk[4][2];
#pragma unroll
    for (int r = 0; r < 4; r++) {
      pk[r][0] = pack2(p[r][0], p[r][1]);
      pk[r][1] = pack2(p[r][2], p[r][3]);
    }

#pragma unroll
    for (int ks2 = 0; ks2 < 2; ++ks2) {
      union {
        unsigned int u[4];
        bf16x8 v;
      } cvt;
#pragma unroll
      for (int dd = 0; dd < 4; ++dd) {
        int src = lo + 16 * ((2 * quad + (dd >> 1)) & 3);
        unsigned int v0 = (unsigned int)__shfl((int)pk[2 * ks2][dd & 1], src);
        unsigned int v1 = (unsigned int)__shfl((int)pk[2 * ks2 + 1][dd & 1], src);
        cvt.u[dd] = (quad >> 1) ? v1 : v0;
      }
      bf16x8 pf = cvt.v;
      __builtin_amdgcn_s_setprio(1);
#pragma unroll
      for (int dt = 0; dt < 16; ++dt) {
        int slot = (ks2 * 4 + quad) ^ (lo & 7);
        bf16x8 vf = *(const bf16x8*)(&Vl[(dt * 16 + lo) * 64 + slot * 8]);
        oacc[dt] = MFMA16(vf, pf, oacc[dt]);
      }
      __builtin_amdgcn_s_setprio(0);
    }
  }

  float inv = 1.0f / l_run;
  unsigned short* cp = C + (size_t)qrow * 256;
#pragma unroll
  for (int dt = 0; dt < 16; ++dt) {
    uint2 v;
    v.x = pack2(oacc[dt][0] * inv, oacc[dt][1] * inv);
    v.y = pack2(oacc[dt][2] * inv, oacc[dt][3] * inv);
    *(uint2*)(cp + dt * 16 + quad * 4) = v;
  }
}

// ---------------- Output projection ----------------
// grid(256) m-blocks, block 512 (8 waves). Full K=256 resident. A (bf16 ctx)
// staged once via async global_load_lds w/ pre-swizzled source; B (fp32 W)
// cvt-staged per n-tile (2 tiles of 128 cols). Wave w -> 64x32, acc[4][2].
__global__ __launch_bounds__(512, 1) void proj_kernel(
    const unsigned short* __restrict__ Xc, const float* __restrict__ W,
    const float* __restrict__ bias, float* __restrict__ out) {
  __shared__ unsigned short Al[128 * 256];
  __shared__ unsigned short Bl[128 * 256];
  const int m0 = blockIdx.x * 128;
  const int t = threadIdx.x;
  const int w = t >> 6, lane = t & 63, lo = lane & 15, quad = lane >> 4;
  const int wr = (w >> 2) * 64, wc = (w & 3) * 32;

  const unsigned short* Xb = Xc + (size_t)m0 * 256;
#pragma unroll
  for (int r = 0; r < 8; ++r) {
    int idx = r * 512 + t;
    int row = idx >> 5, sc = idx & 31;
    int c = (sc & 24) | ((sc ^ (row & 7)) & 7);
    int lofs = __builtin_amdgcn_readfirstlane((r * 512 + w * 64) * 8);
    gl_lds16(Xb + (size_t)row * 256 + c * 8, &Al[lofs]);
  }

  for (int n = 0; n < 2; ++n) {
    const int n0 = n * 128;
    if (n > 0) __syncthreads();
#pragma unroll
    for (int r = 0; r < 8; ++r) {
      int ci = r * 512 + t;
      int row = ci >> 5, c = ci & 31;
      int s = (c & 24) | ((c ^ (row & 7)) & 7);
      const float* wp = W + (size_t)(n0 + row) * 256 + c * 8;
      float4 b0 = *(const float4*)wp, b1 = *(const float4*)(wp + 4);
      uint4 ub;
      ub.x = pack2(b0.x, b0.y);
      ub.y = pack2(b0.z, b0.w);
      ub.z = pack2(b1.x, b1.y);
      ub.w = pack2(b1.z, b1.w);
      *(uint4*)(&Bl[row * 256 + s * 8]) = ub;
    }
    if (n == 0) asm volatile("s_waitcnt vmcnt(0)" ::: "memory");
    __syncthreads();

    f32x4 zero4 = {0.f, 0.f, 0.f, 0.f};
    f32x4 acc[4][2];
#pragma unroll
    for (int i = 0; i < 4; i++)
#pragma unroll
      for (int j = 0; j < 2; j++) acc[i][j] = zero4;

#pragma unroll
    for (int kc = 0; kc < 8; ++kc) {
      const int c = kc * 4 + quad;
      const int jj = (c & 24) | ((c ^ (lo & 7)) & 7);
      bf16x8 af[4], bfr[2];
#pragma unroll
      for (int mt = 0; mt < 4; ++mt)
        af[mt] = *(const bf16x8*)(&Al[(wr + mt * 16 + lo) * 256 + jj * 8]);
#pragma unroll
      for (int nt = 0; nt < 2; ++nt)
        bfr[nt] = *(const bf16x8*)(&Bl[(wc + nt * 16 + lo) * 256 + jj * 8]);
#pragma unroll
      for (int mt = 0; mt < 4; ++mt)
#pragma unroll
        for (int nt = 0; nt < 2; ++nt)
          acc[mt][nt] = MFMA16(af[mt], bfr[nt], acc[mt][nt]);
    }

    const int mb = m0 + wr, nb = n0 + wc;
#pragma unroll
    for (int nt = 0; nt < 2; ++nt) {
      int nn = nb + nt * 16 + lo;
      float bv = bias[nn];
#pragma unroll
      for (int mt = 0; mt < 4; ++mt) {
        int m = mb + mt * 16 + quad * 4;
        float* p = out + (size_t)m * 256 + nn;
        p[0] = acc[mt][nt][0] + bv;
        p[256] = acc[mt][nt][1] + bv;
        p[512] = acc[mt][nt][2] + bv;
        p[768] = acc[mt][nt][3] + bv;
      }
    }
  }
}

extern "C" void kernel_launch(void* const* d_in, const int* in_sizes, int n_in,
                              void* d_out, int out_size, void* d_ws, size_t ws_size,
                              hipStream_t stream) {
  const float* X = (const float*)d_in[0];
  const float* Wq = (const float*)d_in[1];
  const float* Wo = (const float*)d_in[2];
  const float* Bo = (const float*)d_in[3];
  float* out = (float*)d_out;
  unsigned short* ws = (unsigned short*)d_ws;

  const size_t NE = (size_t)16 * 2048 * 256;
  unsigned short* Qb = ws;
  unsigned short* Kb = ws + NE;
  unsigned short* Vt = ws + 2 * NE;
  unsigned short* Cx = ws;              // ctx aliases Q (per-block private rows)
  unsigned short* Wqbf = (unsigned short*)d_out;  // 768*256 bf16 = 384KB, dead
                                                  // until proj overwrites out

  cvtw_kernel<<<dim3(96), 256, 0, stream>>>(Wq, Wqbf);
  qkv_kernel<<<dim3(256), 512, 0, stream>>>(X, Wqbf, Qb, Kb, Vt);
  attn_kernel<<<dim3(256), 512, 0, stream>>>(Qb, Kb, Vt, Cx);
  proj_kernel<<<dim3(256), 512, 0, stream>>>(Cx, Wo, Bo, out);
}

// Round 6
// 204.805 us; speedup vs baseline: 1.1832x; 1.0361x over previous
//
#include <hip/hip_runtime.h>
#include <hip/hip_bf16.h>

// Round 10:
//   k0 cvtw: unchanged (Wq -> bf16 pre-swizzled, in d_out; dead until attn writes out).
//   k1 qkv: 2 blocks/CU (grid 512, 256 thr, 64-row tiles, 64-col B-tiles, 64KB LDS).
//           Two barrier domains/CU -> staging of one block overlaps compute of the
//           other (first structural change to the 1-block/CU serialization).
//   k2 attn: PROJ FUSED INTO EPILOGUE. KV loop identical to round-6 (verified).
//           After loop: ctx stays in registers (Cx never materialized), Wo staged
//           fp32->bf16 into the now-dead 128KB LDS (chunk-XOR swizzled), then
//           out = ctx @ Wo^T + bias via 8 ks x 16 et MFMA16; ctx B-frags built
//           with 8 shfl + 4 sel per ks (same idiom as the P^T build).
//   k3 proj: DELETED (work moved into attn; saves dispatch + 33.6MB HBM traffic).
// ws (ushort): Q[0], K[NE], Vt[2NE], NE=16*2048*256. Wqbf in d_out (384KB).

typedef short bf16x8 __attribute__((ext_vector_type(8)));
typedef float f32x4 __attribute__((ext_vector_type(4)));

#define MFMA16(a, b, c) __builtin_amdgcn_mfma_f32_16x16x32_bf16((a), (b), (c), 0, 0, 0)

__device__ __forceinline__ unsigned short f2bf(float f) {
  unsigned int x;
  __builtin_memcpy(&x, &f, 4);
  x = x + 0x7fffu + ((x >> 16) & 1u);
  return (unsigned short)(x >> 16);
}
__device__ __forceinline__ unsigned int pack2(float a, float b) {
  float2 t;
  t.x = a;
  t.y = b;
  __hip_bfloat162 h = __float22bfloat162_rn(t);
  unsigned int u;
  __builtin_memcpy(&u, &h, 4);
  return u;
}

// async 16B global->LDS. LDS dest is wave-uniform base + lane*16 (HW rule).
typedef __attribute__((address_space(3))) void as3_void;
typedef __attribute__((address_space(1))) const void as1_void;
__device__ __forceinline__ void gl_lds16(const void* g, void* l) {
  __builtin_amdgcn_global_load_lds((as1_void*)(unsigned long long)g,
                                   (as3_void*)(unsigned int)(unsigned long long)l,
                                   16, 0, 0);
}

// ---------------- W_qkv pre-convert (fp32 -> bf16, pre-swizzled) ----------------
__global__ __launch_bounds__(256, 4) void cvtw_kernel(
    const float* __restrict__ W, unsigned short* __restrict__ Wbf) {
  int idx = blockIdx.x * 256 + threadIdx.x;
  int row = idx >> 5, sc = idx & 31;
  int c = (sc & 24) | ((sc ^ (row & 7)) & 7);
  const float* wp = W + (size_t)row * 256 + c * 8;
  float4 a0 = *(const float4*)wp, a1 = *(const float4*)(wp + 4);
  uint4 u;
  u.x = pack2(a0.x, a0.y);
  u.y = pack2(a0.z, a0.w);
  u.z = pack2(a1.x, a1.y);
  u.w = pack2(a1.z, a1.w);
  *(uint4*)(Wbf + (size_t)idx * 8) = u;
}

// ---------------- QKV GEMM, 2 blocks/CU ----------------
// grid(512), block 256 (4 waves). m-tile 64 rows (m0 = bid*64); A in LDS once.
// 12 n-tiles of 64 cols; B staged via pure gl_lds from pre-swizzled Wqbf.
// Wave w -> (wr=(w>>1)*32, wc=(w&1)*32), acc[2][2]. LDS 32+32=64KB -> 2/CU.
__global__ __launch_bounds__(256, 2) void qkv_kernel(
    const float* __restrict__ X, const unsigned short* __restrict__ Wqbf,
    unsigned short* __restrict__ Q, unsigned short* __restrict__ Kp,
    unsigned short* __restrict__ Vt) {
  __shared__ unsigned short Al[64 * 256];  // 32KB
  __shared__ unsigned short Bl[64 * 256];  // 32KB
  const int m0 = blockIdx.x * 64;
  const int t = threadIdx.x;
  const int w = t >> 6, lane = t & 63, lo = lane & 15, quad = lane >> 4;
  const int wr = (w >> 1) * 32, wc = (w & 1) * 32;

  // stage A once: 2048 chunks, 8 per thread (fp32->bf16 cvt, read-once data)
#pragma unroll
  for (int r = 0; r < 8; ++r) {
    int ci = r * 256 + t;
    int row = ci >> 5, c = ci & 31;
    int s = (c & 24) | ((c ^ (row & 7)) & 7);
    const float* xp = X + (size_t)(m0 + row) * 256 + c * 8;
    float4 a0 = *(const float4*)xp, a1 = *(const float4*)(xp + 4);
    uint4 ua;
    ua.x = pack2(a0.x, a0.y);
    ua.y = pack2(a0.z, a0.w);
    ua.z = pack2(a1.x, a1.y);
    ua.w = pack2(a1.z, a1.w);
    *(uint4*)(&Al[row * 256 + s * 8]) = ua;
  }

  const int lofs = __builtin_amdgcn_readfirstlane(w * 64 * 8);
  for (int n = 0; n < 12; ++n) {
    const int n0 = n * 64;
    if (n > 0) __syncthreads();  // prev compute done before overwriting Bl
    // B-stage: pure async gl_lds from pre-swizzled Wqbf (linear source)
    {
      const unsigned short* Wb = Wqbf + (size_t)n0 * 256;
#pragma unroll
      for (int r = 0; r < 8; ++r)
        gl_lds16(Wb + (size_t)(r * 256 + t) * 8, &Bl[r * 256 * 8 + lofs]);
    }
    asm volatile("s_waitcnt vmcnt(0)" ::: "memory");
    __syncthreads();

    f32x4 zero4 = {0.f, 0.f, 0.f, 0.f};
    f32x4 acc[2][2];
#pragma unroll
    for (int i = 0; i < 2; i++)
#pragma unroll
      for (int j = 0; j < 2; j++) acc[i][j] = zero4;

#pragma unroll
    for (int kc = 0; kc < 8; ++kc) {  // K=256 in 8 MFMA steps
      const int c = kc * 4 + quad;
      const int jj = (c & 24) | ((c ^ (lo & 7)) & 7);
      bf16x8 af[2], bfr[2];
#pragma unroll
      for (int mt = 0; mt < 2; ++mt)
        af[mt] = *(const bf16x8*)(&Al[(wr + mt * 16 + lo) * 256 + jj * 8]);
#pragma unroll
      for (int nt = 0; nt < 2; ++nt)
        bfr[nt] = *(const bf16x8*)(&Bl[(wc + nt * 16 + lo) * 256 + jj * 8]);
#pragma unroll
      for (int mt = 0; mt < 2; ++mt)
#pragma unroll
        for (int nt = 0; nt < 2; ++nt)
          acc[mt][nt] = MFMA16(af[mt], bfr[nt], acc[mt][nt]);
    }

    // epilogue for this n-tile (tiles 0-3 -> Q, 4-7 -> K, 8-11 -> Vt)
    const int mb = m0 + wr, nb = n0 + wc;
    if (n0 < 256) {
#pragma unroll
      for (int mt = 0; mt < 2; ++mt)
#pragma unroll
        for (int nt = 0; nt < 2; ++nt) {
          int m = mb + mt * 16 + quad * 4;
          int nn = nb + nt * 16 + lo;
          unsigned short* p = Q + (size_t)m * 256 + nn;
          p[0] = f2bf(acc[mt][nt][0]);
          p[256] = f2bf(acc[mt][nt][1]);
          p[512] = f2bf(acc[mt][nt][2]);
          p[768] = f2bf(acc[mt][nt][3]);
        }
    } else if (n0 < 512) {
#pragma unroll
      for (int mt = 0; mt < 2; ++mt)
#pragma unroll
        for (int nt = 0; nt < 2; ++nt) {
          int m = mb + mt * 16 + quad * 4;
          int nn = nb + nt * 16 + lo - 256;
          unsigned short* p = Kp + (size_t)m * 256 + nn;
          p[0] = f2bf(acc[mt][nt][0]);
          p[256] = f2bf(acc[mt][nt][1]);
          p[512] = f2bf(acc[mt][nt][2]);
          p[768] = f2bf(acc[mt][nt][3]);
        }
    } else {
#pragma unroll
      for (int mt = 0; mt < 2; ++mt)
#pragma unroll
        for (int nt = 0; nt < 2; ++nt) {
          int m = mb + mt * 16 + quad * 4;
          int d = nb + nt * 16 + lo - 512;
          int b = m >> 11, s = m & 2047;
          uint2 v;
          v.x = pack2(acc[mt][nt][0], acc[mt][nt][1]);
          v.y = pack2(acc[mt][nt][2], acc[mt][nt][3]);
          *(uint2*)(Vt + ((size_t)(b * 256 + d)) * 2048 + s) = v;
        }
    }
  }
}

// ---------------- Flash attention + FUSED output projection ----------------
// KV loop: round-6 verbatim (verified). Epilogue: ctx (in regs) @ Wo^T + bias,
// Wo staged fp32->bf16 into the freed 128KB LDS (chunk-XOR swizzle).
__global__ __launch_bounds__(512, 2) void attn_kernel(
    const unsigned short* __restrict__ Q, const unsigned short* __restrict__ K,
    const unsigned short* __restrict__ Vt, const float* __restrict__ Wo,
    const float* __restrict__ bias, float* __restrict__ out) {
  __shared__ __attribute__((aligned(16))) unsigned short smem[65536];  // 131072 B
  const int id = blockIdx.x;
  const int b = id & 15;
  const int qt = id >> 4;
  const int t = threadIdx.x;
  const int w = t >> 6, lane = t & 63, lo = lane & 15, quad = lane >> 4;
  constexpr float SCALE_LOG2E = 0.0625f * 1.4426950408889634f;

  const unsigned short* Kb = K + (size_t)b * 2048 * 256;
  const unsigned short* Vb = Vt + (size_t)b * 256 * 2048;

  unsigned int gkoff[4], gvoff[4];
  int loK[4], loV[4];
#pragma unroll
  for (int r = 0; r < 4; ++r) {
    int ck = r * 512 + t;
    int row = ck >> 5, j = ck & 31;
    int srcj = (j & 16) | ((j ^ (row & 15)) & 15);
    gkoff[r] = (unsigned int)((row * 256 + srcj * 8) * 2);
    loK[r] = __builtin_amdgcn_readfirstlane((r * 512 + w * 64) * 8);

    int cv = r * 512 + t;
    int d = cv >> 3, slot = cv & 7;
    int g = slot ^ (d & 7);
    gvoff[r] = (unsigned int)((d * 2048 + g * 8) * 2);
    loV[r] = __builtin_amdgcn_readfirstlane(16384 + (r * 512 + w * 64) * 8);
  }

  const int qrow = b * 2048 + qt * 128 + w * 16 + lo;
  const unsigned short* qp = Q + (size_t)qrow * 256;
  bf16x8 qf[8];
#pragma unroll
  for (int ks = 0; ks < 8; ++ks)
    qf[ks] = *(const bf16x8*)(qp + ks * 32 + quad * 8);

  f32x4 zero4 = {0.f, 0.f, 0.f, 0.f};
  f32x4 oacc[16];
#pragma unroll
  for (int i = 0; i < 16; i++) oacc[i] = zero4;
  float m_run = -1e30f, l_run = 0.f;

#pragma unroll
  for (int r = 0; r < 4; ++r) {
    gl_lds16((const char*)Kb + gkoff[r], &smem[loK[r]]);
    gkoff[r] += 64 * 256 * 2;
  }
#pragma unroll
  for (int r = 0; r < 4; ++r) {
    gl_lds16((const char*)Vb + gvoff[r], &smem[loV[r]]);
    gvoff[r] += 64 * 2;
  }

  for (int it = 0; it < 32; ++it) {
    asm volatile("s_waitcnt vmcnt(0)" ::: "memory");
    __syncthreads();
    if (it < 31) {
      const int pn = ((it + 1) & 1) * 32768;
#pragma unroll
      for (int r = 0; r < 4; ++r) {
        gl_lds16((const char*)Kb + gkoff[r], &smem[pn + loK[r]]);
        gkoff[r] += 64 * 256 * 2;
      }
#pragma unroll
      for (int r = 0; r < 4; ++r) {
        gl_lds16((const char*)Vb + gvoff[r], &smem[pn + loV[r]]);
        gvoff[r] += 64 * 2;
      }
    }
    const unsigned short* Kl = smem + (it & 1) * 32768;
    const unsigned short* Vl = Kl + 16384;

    f32x4 sacc[4];
#pragma unroll
    for (int r = 0; r < 4; ++r) sacc[r] = zero4;
    __builtin_amdgcn_s_setprio(1);
#pragma unroll
    for (int ks = 0; ks < 8; ++ks) {
      const int c = ks * 4 + quad;
      const int jj = (c & 16) | ((c ^ lo) & 15);
#pragma unroll
      for (int r = 0; r < 4; ++r) {
        bf16x8 kf = *(const bf16x8*)(&Kl[(r * 16 + lo) * 256 + jj * 8]);
        sacc[r] = MFMA16(kf, qf[ks], sacc[r]);
      }
    }
    __builtin_amdgcn_s_setprio(0);

    float p[4][4];
    float cmax = -1e30f;
#pragma unroll
    for (int r = 0; r < 4; r++)
#pragma unroll
      for (int i = 0; i < 4; i++) {
        p[r][i] = sacc[r][i] * SCALE_LOG2E;
        cmax = fmaxf(cmax, p[r][i]);
      }
    cmax = fmaxf(cmax, __shfl_xor(cmax, 16));
    cmax = fmaxf(cmax, __shfl_xor(cmax, 32));
    if (!__all(cmax <= m_run + 8.f)) {
      float mnew = fmaxf(m_run, cmax);
      float alpha = exp2f(m_run - mnew);
      l_run *= alpha;
#pragma unroll
      for (int i = 0; i < 16; i++) oacc[i] *= alpha;
      m_run = mnew;
    }
    float rsum = 0.f;
#pragma unroll
    for (int r = 0; r < 4; r++)
#pragma unroll
      for (int i = 0; i < 4; i++) {
        p[r][i] = exp2f(p[r][i] - m_run);
        rsum += p[r][i];
      }
    rsum += __shfl_xor(rsum, 16);
    rsum += __shfl_xor(rsum, 32);
    l_run += rsum;

    unsigned int pk[4][2];
#pragma unroll
    for (int r = 0; r < 4; r++) {
      pk[r][0] = pack2(p[r][0], p[r][1]);
      pk[r][1] = pack2(p[r][2], p[r][3]);
    }

#pragma unroll
    for (int ks2 = 0; ks2 < 2; ++ks2) {
      union {
        unsigned int u[4];
        bf16x8 v;
      } cvt;
#pragma unroll
      for (int dd = 0; dd < 4; ++dd) {
        int src = lo + 16 * ((2 * quad + (dd >> 1)) & 3);
        unsigned int v0 = (unsigned int)__shfl((int)pk[2 * ks2][dd & 1], src);
        unsigned int v1 = (unsigned int)__shfl((int)pk[2 * ks2 + 1][dd & 1], src);
        cvt.u[dd] = (quad >> 1) ? v1 : v0;
      }
      bf16x8 pf = cvt.v;
      __builtin_amdgcn_s_setprio(1);
#pragma unroll
      for (int dt = 0; dt < 16; ++dt) {
        int slot = (ks2 * 4 + quad) ^ (lo & 7);
        bf16x8 vf = *(const bf16x8*)(&Vl[(dt * 16 + lo) * 64 + slot * 8]);
        oacc[dt] = MFMA16(vf, pf, oacc[dt]);
      }
      __builtin_amdgcn_s_setprio(0);
    }
  }

  // ================= fused output projection =================
  // ctx[q=lo][d=dt*16+quad*4+i] = oacc[dt][i]/l_run  (stays in registers).
  float inv = 1.0f / l_run;
  uint2 c2[16];  // bf16 ctx pairs; oacc dead after this
#pragma unroll
  for (int dt = 0; dt < 16; ++dt) {
    c2[dt].x = pack2(oacc[dt][0] * inv, oacc[dt][1] * inv);
    c2[dt].y = pack2(oacc[dt][2] * inv, oacc[dt][3] * inv);
  }

  __syncthreads();  // everyone done with K/V smem
  // stage Wo fp32 -> bf16 into smem, chunk-XOR swizzled ([256 e][256 d], 128KB)
#pragma unroll
  for (int r = 0; r < 16; ++r) {
    int ci = r * 512 + t;
    int row = ci >> 5, c = ci & 31;
    int s = (c & 24) | ((c ^ (row & 7)) & 7);
    const float* wp = Wo + (size_t)row * 256 + c * 8;
    float4 a0 = *(const float4*)wp, a1 = *(const float4*)(wp + 4);
    uint4 ua;
    ua.x = pack2(a0.x, a0.y);
    ua.y = pack2(a0.z, a0.w);
    ua.z = pack2(a1.x, a1.y);
    ua.w = pack2(a1.z, a1.w);
    *(uint4*)(&smem[row * 256 + s * 8]) = ua;
  }
  __syncthreads();

  // out[q][e] = sum_d ctx[q][d] * Wo[e][d] + bias[e]
  f32x4 outacc[16];
#pragma unroll
  for (int i = 0; i < 16; i++) outacc[i] = zero4;

#pragma unroll
  for (int ks = 0; ks < 8; ++ks) {
    // B-frag: lane needs ctx[q=lo][d = ks*32 + quad*8 + j], j=0..7.
    // dt' = 2ks + (quad>>1); first 4 j from quad qa=(quad&1)*2, next 4 from qa+1.
    int sa = lo + 16 * ((quad & 1) * 2);
    unsigned int xA = (unsigned int)__shfl((int)c2[2 * ks].x, sa);
    unsigned int yA = (unsigned int)__shfl((int)c2[2 * ks].y, sa);
    unsigned int xB = (unsigned int)__shfl((int)c2[2 * ks].x, sa + 16);
    unsigned int yB = (unsigned int)__shfl((int)c2[2 * ks].y, sa + 16);
    unsigned int xA1 = (unsigned int)__shfl((int)c2[2 * ks + 1].x, sa);
    unsigned int yA1 = (unsigned int)__shfl((int)c2[2 * ks + 1].y, sa);
    unsigned int xB1 = (unsigned int)__shfl((int)c2[2 * ks + 1].x, sa + 16);
    unsigned int yB1 = (unsigned int)__shfl((int)c2[2 * ks + 1].y, sa + 16);
    union {
      unsigned int u[4];
      bf16x8 v;
    } cvt;
    bool hiq = (quad >> 1) != 0;
    cvt.u[0] = hiq ? xA1 : xA;
    cvt.u[1] = hiq ? yA1 : yA;
    cvt.u[2] = hiq ? xB1 : xB;
    cvt.u[3] = hiq ? yB1 : yB;
    bf16x8 pf = cvt.v;

    const int c = ks * 4 + quad;
    const int jj = (c & 24) | ((c ^ (lo & 7)) & 7);
    __builtin_amdgcn_s_setprio(1);
#pragma unroll
    for (int et = 0; et < 16; ++et) {
      bf16x8 af = *(const bf16x8*)(&smem[(et * 16 + lo) * 256 + jj * 8]);
      outacc[et] = MFMA16(af, pf, outacc[et]);
    }
    __builtin_amdgcn_s_setprio(0);
  }

  // store: C-layout col=q=lo, row=e=et*16+quad*4+i -> float4 per (et)
  float* op = out + (size_t)qrow * 256;
#pragma unroll
  for (int et = 0; et < 16; ++et) {
    const float4 b4 = *(const float4*)(bias + et * 16 + quad * 4);
    float4 v;
    v.x = outacc[et][0] + b4.x;
    v.y = outacc[et][1] + b4.y;
    v.z = outacc[et][2] + b4.z;
    v.w = outacc[et][3] + b4.w;
    *(float4*)(op + et * 16 + quad * 4) = v;
  }
}

extern "C" void kernel_launch(void* const* d_in, const int* in_sizes, int n_in,
                              void* d_out, int out_size, void* d_ws, size_t ws_size,
                              hipStream_t stream) {
  const float* X = (const float*)d_in[0];
  const float* Wq = (const float*)d_in[1];
  const float* Wo = (const float*)d_in[2];
  const float* Bo = (const float*)d_in[3];
  float* out = (float*)d_out;
  unsigned short* ws = (unsigned short*)d_ws;

  const size_t NE = (size_t)16 * 2048 * 256;
  unsigned short* Qb = ws;
  unsigned short* Kb = ws + NE;
  unsigned short* Vt = ws + 2 * NE;
  unsigned short* Wqbf = (unsigned short*)d_out;  // 384KB, dead until attn
                                                  // writes out (after qkv reads)

  cvtw_kernel<<<dim3(96), 256, 0, stream>>>(Wq, Wqbf);
  qkv_kernel<<<dim3(512), 256, 0, stream>>>(X, Wqbf, Qb, Kb, Vt);
  attn_kernel<<<dim3(256), 512, 0, stream>>>(Qb, Kb, Vt, Wo, Bo, out);
}